// Round 5
// baseline (112.480 us; speedup 1.0000x reference)
//
#include <hip/hip_runtime.h>
#include <stdint.h>

// VectorQuantizer: x[32,64,64,64] NCHW fp32, W[512,64] fp32.
// argmin_k ||x - w_k||^2 ; out = W[argmin] in NCHW.
//
// v5: 1024-thr blocks (16 waves, 256 tokens), full 64KiB swizzled bf16 codebook
// static in LDS, B-frags direct from global (x read once, no LDS transpose),
// error-corrected scores s = (xh+xl)·wh - 0.5||w||^2 via 4 MFMA/ktile,
// hard-certified margin 2^-8*||x||*Wmax + 0.01, always-rescan candidate masks,
// fp64 refine for multi-candidate tokens, direct coalesced epilogue.

typedef short short8 __attribute__((ext_vector_type(8)));
typedef float f32x4 __attribute__((ext_vector_type(4)));

#define HW_ 4096
#define K_ 512
#define D_ 64

__device__ __forceinline__ unsigned short f2bf(float f) {
    unsigned u = __float_as_uint(f);
    u += 0x7fff + ((u >> 16) & 1);   // RNE to bf16
    return (unsigned short)(u >> 16);
}
__device__ __forceinline__ float bf2f(unsigned short h) {
    return __uint_as_float(((unsigned)h) << 16);
}

// Swizzled codebook image: code k, dim d: ushort index
//   (k>>7)*8192 + (k&127)*64 + (((d>>3) ^ (k&7))<<3) + (d&7)
__global__ __launch_bounds__(1024) void vq_prep(const float* __restrict__ W,
                                                unsigned short* __restrict__ Wb,
                                                float* __restrict__ nh,
                                                float* __restrict__ wmax2) {
    __shared__ float wred[8];
    const int tid = threadIdx.x;
    float s = 0.f;
    if (tid < 512) {
        const int k = tid;
        const unsigned kb = (k >> 7) * 8192 + (k & 127) * 64;
        const unsigned sw = k & 7;
        #pragma unroll
        for (int db = 0; db < 8; ++db) {
            f32x4 v0 = *(const f32x4*)(W + k * 64 + db * 8);
            f32x4 v1 = *(const f32x4*)(W + k * 64 + db * 8 + 4);
            unsigned short hb[8];
            #pragma unroll
            for (int e = 0; e < 4; ++e) {
                s += v0[e] * v0[e] + v1[e] * v1[e];
                hb[e] = f2bf(v0[e]);
                hb[e + 4] = f2bf(v1[e]);
            }
            unsigned* dst = (unsigned*)(Wb + kb + ((db ^ sw) << 3));
            dst[0] = hb[0] | ((unsigned)hb[1] << 16);
            dst[1] = hb[2] | ((unsigned)hb[3] << 16);
            dst[2] = hb[4] | ((unsigned)hb[5] << 16);
            dst[3] = hb[6] | ((unsigned)hb[7] << 16);
        }
        nh[k] = -0.5f * s;
    }
    // block max of ||w||^2
    float mx = s;
    #pragma unroll
    for (int off = 1; off < 64; off <<= 1) mx = fmaxf(mx, __shfl_xor(mx, off));
    if (tid < 512 && (tid & 63) == 0) wred[tid >> 6] = mx;
    __syncthreads();
    if (tid < 8) {
        float v = wred[tid];
        #pragma unroll
        for (int off = 1; off < 8; off <<= 1) v = fmaxf(v, __shfl_xor(v, off));
        if (tid == 0) *wmax2 = v;
    }
}

__global__ __launch_bounds__(1024, 8) void vq_main(const float* __restrict__ x,
                                                   const float* __restrict__ W,
                                                   const unsigned short* __restrict__ Wb,
                                                   const float* __restrict__ nh,
                                                   const float* __restrict__ wmax2p,
                                                   float* __restrict__ out) {
    __shared__ unsigned short cb[32768];   // 64 KiB swizzled codebook
    __shared__ float nhs[512];             // -0.5*||w||^2
    __shared__ int bkArr[256];

    const int tid = threadIdx.x;
    const int bid = blockIdx.x;
    const int b = bid >> 4;                  // batch 0..31
    const int p0 = (bid & 15) << 8;          // 256-token spatial base
    const int l = tid & 63;
    const int wv = tid >> 6;                 // wave 0..15
    const int g = l >> 4;                    // k-dim group 0..3
    const int tokw = l & 15;
    const int tok = wv * 16 + tokw;          // 0..255

    // ---- stage codebook + nhs (linear copy; image pre-swizzled) ----
    {
        const f32x4* src = (const f32x4*)Wb;
        f32x4* dst = (f32x4*)cb;
        f32x4 t0 = src[tid], t1 = src[tid + 1024], t2 = src[tid + 2048], t3 = src[tid + 3072];
        dst[tid] = t0; dst[tid + 1024] = t1; dst[tid + 2048] = t2; dst[tid + 3072] = t3;
        if (tid < 128) ((f32x4*)nhs)[tid] = ((const f32x4*)nh)[tid];
    }

    // ---- B fragments direct from global: xh = bf16(x), xl = bf16(x - xh) ----
    short8 bh0, bh1, bl0, bl1;
    float xsq = 0.f;
    const float* xb = x + (size_t)b * 262144 + p0 + tok;
    #pragma unroll
    for (int e = 0; e < 8; ++e) {
        float v = xb[(size_t)(g * 8 + e) * HW_];
        xsq += v * v;
        unsigned short h = f2bf(v);
        bh0[e] = (short)h;
        bl0[e] = (short)f2bf(v - bf2f(h));
    }
    #pragma unroll
    for (int e = 0; e < 8; ++e) {
        float v = xb[(size_t)(32 + g * 8 + e) * HW_];
        xsq += v * v;
        unsigned short h = f2bf(v);
        bh1[e] = (short)h;
        bl1[e] = (short)f2bf(v - bf2f(h));
    }
    xsq += __shfl_xor(xsq, 16);
    xsq += __shfl_xor(xsq, 32);
    const float margin = ldexpf(sqrtf(xsq * (*wmax2p)), -8) + 0.01f;  // 2*2^-9*||x||*Wmax + slack
    __syncthreads();

    // LDS byte offsets: A-read for ktile t is (cbB + t*2048 + off) -- swizzle is
    // lane-constant because (t*16+tokw)&7 == tokw&7.
    const char* cbB = (const char*)cb;
    const unsigned off0 = tokw * 128 + 16 * (g ^ (tokw & 7));
    const unsigned off1 = tokw * 128 + 16 * ((g + 4) ^ (tokw & 7));

    #define KTILE(T, ACC) {                                                          \
        short8 a0 = *(const short8*)(cbB + (T) * 2048 + off0);                       \
        short8 a1 = *(const short8*)(cbB + (T) * 2048 + off1);                       \
        ACC = *(const f32x4*)(&nhs[(T) * 16 + g * 4]);                               \
        ACC = __builtin_amdgcn_mfma_f32_16x16x32_bf16(a0, bh0, ACC, 0, 0, 0);        \
        ACC = __builtin_amdgcn_mfma_f32_16x16x32_bf16(a0, bl0, ACC, 0, 0, 0);        \
        ACC = __builtin_amdgcn_mfma_f32_16x16x32_bf16(a1, bh1, ACC, 0, 0, 0);        \
        ACC = __builtin_amdgcn_mfma_f32_16x16x32_bf16(a1, bl1, ACC, 0, 0, 0);        \
    }

    // ---- pass 1: running maxes only ----
    float m0 = -3.4e38f, m1 = -3.4e38f, m2 = -3.4e38f, m3 = -3.4e38f;
    #pragma unroll
    for (int t = 0; t < 32; ++t) {
        f32x4 acc;
        KTILE(t, acc);
        m0 = fmaxf(m0, acc[0]); m1 = fmaxf(m1, acc[1]);
        m2 = fmaxf(m2, acc[2]); m3 = fmaxf(m3, acc[3]);
    }
    float m = fmaxf(fmaxf(m0, m1), fmaxf(m2, m3));
    m = fmaxf(m, __shfl_xor(m, 16));
    m = fmaxf(m, __shfl_xor(m, 32));
    const float thr = m - margin;

    // ---- pass 2: rescan, build candidate masks (slot = t*4 + r) ----
    uint64_t c0m = 0, c1m = 0;
    #pragma unroll
    for (int t = 0; t < 32; ++t) {
        f32x4 acc;
        KTILE(t, acc);
        uint64_t bits = 0;
        #pragma unroll
        for (int r = 0; r < 4; ++r)
            bits |= (uint64_t)(acc[r] >= thr ? 1u : 0u) << r;
        if (t < 16) c0m |= bits << (t * 4);
        else        c1m |= bits << ((t - 16) * 4);
    }
    #undef KTILE

    int cnt = __popcll(c0m) + __popcll(c1m);
    int cnt4 = cnt;
    cnt4 += __shfl_xor(cnt4, 16);
    cnt4 += __shfl_xor(cnt4, 32);

    // singleton: the lone candidate is provably the exact argmin
    int klocal = 0x7fffffff;
    if (cnt == 1) {
        int slot, hi;
        if (c0m) { slot = __builtin_ctzll(c0m); hi = 0; }
        else     { slot = __builtin_ctzll(c1m); hi = 1; }
        klocal = ((slot >> 2) + hi * 16) * 16 + g * 4 + (slot & 3);
    }
    int kmin = klocal;
    kmin = min(kmin, __shfl_xor(kmin, 16));
    kmin = min(kmin, __shfl_xor(kmin, 32));

    // multi-candidate: exact fp64 sum((x-w)^2), wave-cooperative, x from global
    double bd = 1.0e308;
    int bkm = 0x7fffffff;
    const bool multi = (cnt4 > 1);
    if (!multi) { c0m = 0; c1m = 0; }
    uint64_t wmask = __ballot((c0m | c1m) != 0ull);
    const float* xcol = x + (size_t)b * 262144 + p0;
    while (wmask) {
        int L = __builtin_ctzll(wmask);
        wmask &= wmask - 1;
        uint64_t mm0 = __shfl(c0m, L);
        uint64_t mm1 = __shfl(c1m, L);
        int gL = L >> 4;
        double xvd = (double)xcol[(size_t)l * HW_ + wv * 16 + (L & 15)];
        while (mm0 | mm1) {
            int k;
            if (mm0) {
                int s2 = __builtin_ctzll(mm0); mm0 &= mm0 - 1;
                k = (s2 >> 2) * 16 + gL * 4 + (s2 & 3);
            } else {
                int s2 = __builtin_ctzll(mm1); mm1 &= mm1 - 1;
                k = ((s2 >> 2) + 16) * 16 + gL * 4 + (s2 & 3);
            }
            double dl = xvd - (double)W[k * 64 + l];
            double p = dl * dl;
            #pragma unroll
            for (int off = 1; off < 64; off <<= 1) p += __shfl_xor(p, off);
            if (l == L && (p < bd || (p == bd && k < bkm))) { bd = p; bkm = k; }
        }
    }
    {   // lexicographic (dist, k) merge across the 4 lanes of each token
        double od = __shfl_xor(bd, 16); int ok = __shfl_xor(bkm, 16);
        if (od < bd || (od == bd && ok < bkm)) { bd = od; bkm = ok; }
        od = __shfl_xor(bd, 32); ok = __shfl_xor(bkm, 32);
        if (od < bd || (od == bd && ok < bkm)) { bd = od; bkm = ok; }
    }
    const int bk = multi ? bkm : kmin;

    if (g == 0) bkArr[tok] = bk;
    __syncthreads();

    // ---- epilogue: gather W rows from L2, store direct to NCHW (coalesced) ----
    {
        const int pp = tid & 255;            // token
        const int dq = tid >> 8;             // dim quarter 0..3
        const int kk = bkArr[pp];
        const float* wr = W + kk * 64 + dq * 16;
        float* ob = out + (size_t)b * 262144 + p0 + pp;
        #pragma unroll
        for (int j = 0; j < 4; ++j) {
            f32x4 v = *(const f32x4*)(wr + j * 4);
            ob[(size_t)(dq * 16 + j * 4 + 0) * HW_] = v[0];
            ob[(size_t)(dq * 16 + j * 4 + 1) * HW_] = v[1];
            ob[(size_t)(dq * 16 + j * 4 + 2) * HW_] = v[2];
            ob[(size_t)(dq * 16 + j * 4 + 3) * HW_] = v[3];
        }
    }
}

extern "C" void kernel_launch(void* const* d_in, const int* in_sizes, int n_in,
                              void* d_out, int out_size, void* d_ws, size_t ws_size,
                              hipStream_t stream) {
    const float* x = (const float*)d_in[0];
    const float* W = (const float*)d_in[1];
    unsigned short* Wb = (unsigned short*)d_ws;                 // 64 KiB swizzled bf16
    float* nh = (float*)((char*)d_ws + 65536);                  // 512 f32
    float* wmax2 = (float*)((char*)d_ws + 65536 + 2048);        // 1 f32
    vq_prep<<<1, 1024, 0, stream>>>(W, Wb, nh, wmax2);
    vq_main<<<512, 1024, 0, stream>>>(x, W, Wb, nh, wmax2, (float*)d_out);
}